// Round 2
// baseline (2288.370 us; speedup 1.0000x reference)
//
#include <hip/hip_runtime.h>

#define NUSERS 100000
#define NITEMS 50000
#define NN (NUSERS + NITEMS)          // 150000 nodes
#define D 64
#define NE 6400000
#define QB 1024
#define RS_PAD 150016                  // padded row_start length
#define BS 128                         // nodes per dst-bucket
#define NB ((NN + BS - 1) / BS)        // 1172 buckets

__global__ void zero_kernel(int* __restrict__ p, int n) {
    for (int i = blockIdx.x * blockDim.x + threadIdx.x; i < n;
         i += gridDim.x * blockDim.x)
        p[i] = 0;
}

__global__ void hist_kernel(const int* __restrict__ dst, int* __restrict__ cnt, int n) {
    for (int i = blockIdx.x * blockDim.x + threadIdx.x; i < n;
         i += gridDim.x * blockDim.x)
        atomicAdd(&cnt[dst[i]], 1);
}

// ---------------------------------------------------------------------------
// single-block exclusive scan, 16 elems/thread per chunk (10 chunks for 150K)
// ---------------------------------------------------------------------------
__global__ __launch_bounds__(1024) void scan_kernel(const int* __restrict__ cnt,
                                                    int* __restrict__ row_start, int nn) {
    __shared__ int wsum[16];
    __shared__ int s_carry, s_tot;
    const int t = threadIdx.x;
    const int lane = t & 63;
    const int wid = t >> 6;
    if (t == 0) s_carry = 0;
    __syncthreads();
    const int CH = 16384;
    for (int chunk = 0; chunk < nn; chunk += CH) {
        const int i0 = chunk + t * 16;
        int c[16];
        if (i0 + 16 <= nn) {
#pragma unroll
            for (int q = 0; q < 4; ++q) {
                int4 v = *reinterpret_cast<const int4*>(cnt + i0 + q * 4);
                c[q * 4 + 0] = v.x; c[q * 4 + 1] = v.y;
                c[q * 4 + 2] = v.z; c[q * 4 + 3] = v.w;
            }
        } else {
#pragma unroll
            for (int q = 0; q < 16; ++q) c[q] = (i0 + q < nn) ? cnt[i0 + q] : 0;
        }
        int v = 0;
#pragma unroll
        for (int q = 0; q < 16; ++q) v += c[q];
        int s = v;
#pragma unroll
        for (int off = 1; off < 64; off <<= 1) {
            int y = __shfl_up(s, off, 64);
            if (lane >= off) s += y;
        }
        if (lane == 63) wsum[wid] = s;
        __syncthreads();
        if (t < 16) {
            int w = wsum[t];
            int ss = w;
#pragma unroll
            for (int off = 1; off < 16; off <<= 1) {
                int y = __shfl_up(ss, off, 16);
                if (t >= off) ss += y;
            }
            wsum[t] = ss - w;
            if (t == 15) s_tot = ss;
        }
        __syncthreads();
        int run = s_carry + wsum[wid] + (s - v);
        int o[16];
#pragma unroll
        for (int q = 0; q < 16; ++q) { o[q] = run; run += c[q]; }
        if (i0 + 16 <= nn) {
#pragma unroll
            for (int q = 0; q < 4; ++q)
                *reinterpret_cast<int4*>(row_start + i0 + q * 4) =
                    make_int4(o[q * 4], o[q * 4 + 1], o[q * 4 + 2], o[q * 4 + 3]);
        } else {
#pragma unroll
            for (int q = 0; q < 16; ++q) if (i0 + q < nn) row_start[i0 + q] = o[q];
        }
        __syncthreads();
        if (t == 0) s_carry += s_tot;
        __syncthreads();
    }
    if (t == 0) row_start[nn] = s_carry;
}

__global__ void bcur_init_kernel(const int* __restrict__ row_start, int* __restrict__ bcur) {
    int b = blockIdx.x * blockDim.x + threadIdx.x;
    if (b < NB) bcur[b] = row_start[b * BS];
}

// ---------------------------------------------------------------------------
// phase A: append edges to their dst-bucket region (write fronts = 1172 lines,
// all L2-resident; packed 8B payload -> ~1x write amplification)
// ---------------------------------------------------------------------------
__global__ void phaseA_kernel(const int* __restrict__ src, const int* __restrict__ dst,
                              const float* __restrict__ val, int* __restrict__ bcur,
                              int2* __restrict__ tmp, int n) {
    for (int i = blockIdx.x * blockDim.x + threadIdx.x; i < n;
         i += gridDim.x * blockDim.x) {
        int d = dst[i];
        int bkt = d >> 7;                    // BS = 128
        int pos = atomicAdd(&bcur[bkt], 1);
        tmp[pos] = make_int2(src[i] | ((d & (BS - 1)) << 20), __float_as_int(val[i]));
    }
}

// ---------------------------------------------------------------------------
// phase B: within-bucket exact placement via LDS cursors (LDS atomics).
// Write window per bucket ~44 KB, L2-resident. 512 blocks bound concurrency.
// ---------------------------------------------------------------------------
__global__ __launch_bounds__(256) void phaseB_kernel(const int2* __restrict__ tmp,
                                                     const int* __restrict__ row_start,
                                                     int2* __restrict__ csr) {
    __shared__ int cur[BS];
    for (int b = blockIdx.x; b < NB; b += gridDim.x) {
        const int node0 = b * BS;
        const int nloc = min(BS, NN - node0);
        for (int j = threadIdx.x; j < nloc; j += blockDim.x)
            cur[j] = row_start[node0 + j];
        __syncthreads();
        const int bs = row_start[node0];
        const int be = row_start[node0 + nloc];
        for (int i = bs + threadIdx.x; i < be; i += blockDim.x) {
            int2 e = tmp[i];
            int dl = e.x >> 20;              // e.x < 2^27, positive
            int pos = atomicAdd(&cur[dl], 1);
            csr[pos] = make_int2(e.x & 0xFFFFF, e.y);
        }
        __syncthreads();
    }
}

// ---------------------------------------------------------------------------
// SpMM: one wave per dst row, lane = dim. M=0: first layer (reads emb tables,
// initializes acc = x0 + x1). M=1: middle. M=2: last (no xout write).
// ---------------------------------------------------------------------------
template <int M>
__global__ __launch_bounds__(256) void spmm_kernel(const float* __restrict__ ue,
                                                   const float* __restrict__ ie,
                                                   const float* __restrict__ x,
                                                   float* __restrict__ xout,
                                                   float* __restrict__ acc,
                                                   const int* __restrict__ row_start,
                                                   const int2* __restrict__ csr) {
    int wave = (blockIdx.x << 2) | (threadIdx.x >> 6);
    int row = __builtin_amdgcn_readfirstlane(wave);
    if (row >= NN) return;
    const int lane = threadIdx.x & 63;
    int b = __builtin_amdgcn_readfirstlane(row_start[row]);
    int e = __builtin_amdgcn_readfirstlane(row_start[row + 1]);
    float a = 0.f;
    int i = b;
#define SRCROW(s) (M == 0 ? ((s) < NUSERS ? ue + (size_t)(s) * D : ie + (size_t)((s) - NUSERS) * D) \
                          : x + (size_t)(s) * D)
    for (; i + 4 <= e; i += 4) {
        int2 e0 = csr[i], e1 = csr[i + 1], e2 = csr[i + 2], e3 = csr[i + 3];
        a = fmaf(__int_as_float(e0.y), SRCROW(e0.x)[lane], a);
        a = fmaf(__int_as_float(e1.y), SRCROW(e1.x)[lane], a);
        a = fmaf(__int_as_float(e2.y), SRCROW(e2.x)[lane], a);
        a = fmaf(__int_as_float(e3.y), SRCROW(e3.x)[lane], a);
    }
    for (; i < e; ++i) {
        int2 e0 = csr[i];
        a = fmaf(__int_as_float(e0.y), SRCROW(e0.x)[lane], a);
    }
#undef SRCROW
    size_t o = (size_t)row * D + lane;
    if (M == 0) {
        float v = (row < NUSERS) ? ue[(size_t)row * D + lane]
                                 : ie[(size_t)(row - NUSERS) * D + lane];
        acc[o] = v + a;
        xout[o] = a;
    } else if (M == 1) {
        acc[o] += a;
        xout[o] = a;
    } else {
        acc[o] += a;
    }
}

__global__ void copy_items_kernel(const float4* __restrict__ acc4, float4* __restrict__ items4) {
    const int TOT4 = NITEMS * (D / 4);
    const int BASE4 = NUSERS * (D / 4);
    for (int i = blockIdx.x * blockDim.x + threadIdx.x; i < TOT4;
         i += gridDim.x * blockDim.x)
        items4[i] = acc4[BASE4 + i];
}

__global__ void ug_kernel(const float4* __restrict__ acc4, const int* __restrict__ users,
                          float4* __restrict__ ug4) {
    int i = blockIdx.x * blockDim.x + threadIdx.x;   // [0, QB*16)
    if (i >= QB * (D / 4)) return;
    int b = i >> 4;
    int k = i & 15;
    float4 v = acc4[(size_t)users[b] * (D / 4) + k];
    const float sc = 1.0f / 16.0f;                    // two folded /4 means
    ug4[i] = make_float4(v.x * sc, v.y * sc, v.z * sc, v.w * sc);
}

__global__ __launch_bounds__(256) void rating_kernel(const float* __restrict__ items_s,
                                                     const float* __restrict__ ug,
                                                     float* __restrict__ out) {
    const int i = blockIdx.x * 256 + threadIdx.x;
    const bool valid = i < NITEMS;
    const int ic = valid ? i : 0;
    float4 ir[16];
    const float4* irow = reinterpret_cast<const float4*>(items_s) + (size_t)ic * (D / 4);
#pragma unroll
    for (int k = 0; k < 16; ++k) ir[k] = irow[k];
    const float4* ug4 = reinterpret_cast<const float4*>(ug);
    const int u0 = blockIdx.y * 128;
    for (int g = 0; g < 16; ++g) {
        const int ub = u0 + g * 8;
        float s[8];
#pragma unroll
        for (int j = 0; j < 8; ++j) s[j] = 0.f;
#pragma unroll
        for (int k = 0; k < 16; ++k) {
            const float4 iv = ir[k];
#pragma unroll
            for (int j = 0; j < 8; ++j) {
                const float4 uv = ug4[(ub + j) * (D / 4) + k];
                s[j] = fmaf(iv.x, uv.x, s[j]);
                s[j] = fmaf(iv.y, uv.y, s[j]);
                s[j] = fmaf(iv.z, uv.z, s[j]);
                s[j] = fmaf(iv.w, uv.w, s[j]);
            }
        }
        if (valid) {
#pragma unroll
            for (int j = 0; j < 8; ++j) {
                float r = 1.0f / (1.0f + __expf(-s[j]));
                out[(size_t)(ub + j) * NITEMS + i] = r;
            }
        }
    }
}

extern "C" void kernel_launch(void* const* d_in, const int* in_sizes, int n_in,
                              void* d_out, int out_size, void* d_ws, size_t ws_size,
                              hipStream_t stream) {
    const float* user_emb = (const float*)d_in[0];
    const float* item_emb = (const float*)d_in[1];
    const float* edge_val = (const float*)d_in[2];
    const int*   edge_src = (const int*)d_in[3];
    const int*   edge_dst = (const int*)d_in[4];
    const int*   users    = (const int*)d_in[5];

    // d_out (51.2M floats) doubles as scratch; rating_kernel rewrites all of it
    // and reads only from d_ws.
    float* ob  = (float*)d_out;
    float* x0  = ob;                                   //  9.6M f (also tmp, pre-init)
    float* x1  = x0 + (size_t)NN * D;                  //  9.6M f (also tmp tail)
    float* acc = x1 + (size_t)NN * D;                  //  9.6M f
    int2*  csr = (int2*)(acc + (size_t)NN * D);        //  6.4M int2 (51.2 MB)
    int*   row_start = (int*)(csr + NE);               //  NN+1 (padded)
    int*   cnt  = row_start + RS_PAD;                  //  NN (padded)
    int*   bcur = cnt + RS_PAD;                        //  NB
    int2*  tmp  = (int2*)x0;                           //  6.4M int2 over x0+x1 region

    // d_ws: only what rating_kernel reads (~13.1 MB)
    float* items_s = (float*)d_ws;                     // NITEMS*D
    float* ug      = items_s + (size_t)NITEMS * D;     // QB*D

    zero_kernel<<<256, 256, 0, stream>>>(cnt, NN);
    hist_kernel<<<2048, 256, 0, stream>>>(edge_dst, cnt, NE);
    scan_kernel<<<1, 1024, 0, stream>>>(cnt, row_start, NN);
    bcur_init_kernel<<<(NB + 255) / 256, 256, 0, stream>>>(row_start, bcur);
    phaseA_kernel<<<2048, 256, 0, stream>>>(edge_src, edge_dst, edge_val, bcur, tmp, NE);
    phaseB_kernel<<<512, 256, 0, stream>>>(tmp, row_start, csr);

    // 3 propagation layers (wave per row); layer 1 reads emb tables directly
    spmm_kernel<0><<<37500, 256, 0, stream>>>(user_emb, item_emb, nullptr, x1, acc,
                                              row_start, csr);
    spmm_kernel<1><<<37500, 256, 0, stream>>>(nullptr, nullptr, x1, x0, acc,
                                              row_start, csr);
    spmm_kernel<2><<<37500, 256, 0, stream>>>(nullptr, nullptr, x0, nullptr, acc,
                                              row_start, csr);

    copy_items_kernel<<<1024, 256, 0, stream>>>((const float4*)acc, (float4*)items_s);
    ug_kernel<<<64, 256, 0, stream>>>((const float4*)acc, users, (float4*)ug);

    rating_kernel<<<dim3((NITEMS + 255) / 256, QB / 128), 256, 0, stream>>>(items_s, ug, (float*)d_out);
}

// Round 3
// 1087.260 us; speedup vs baseline: 2.1047x; 2.1047x over previous
//
#include <hip/hip_runtime.h>

#define NUSERS 100000
#define NITEMS 50000
#define NN (NUSERS + NITEMS)          // 150000 nodes
#define D 64
#define NE 6400000
#define QB 1024
#define PSZ 256                        // nodes per partition
#define NP ((NN + PSZ - 1) / PSZ)      // 586 partitions
#define NBLKB 256                      // countB/placeB blocks
#define EPB (NE / NBLKB)               // 25000 edges per block (exact)
#define CNTN (NP * NBLKB)              // 150016 counts

// ---------------------------------------------------------------------------
// countB: per-block LDS histogram over partitions -> counts[p][b]. No global
// atomics anywhere in the CSR build.
// ---------------------------------------------------------------------------
__global__ __launch_bounds__(256) void countB_kernel(const int* __restrict__ dst,
                                                     int* __restrict__ counts) {
    __shared__ int hist[NP];
    const int t = threadIdx.x, b = blockIdx.x;
    for (int j = t; j < NP; j += 256) hist[j] = 0;
    __syncthreads();
    const int e0 = b * EPB, e1 = e0 + EPB;
    for (int i = e0 + t; i < e1; i += 256)
        atomicAdd(&hist[dst[i] >> 8], 1);            // LDS atomic
    __syncthreads();
    for (int j = t; j < NP; j += 256)
        counts[j * NBLKB + b] = hist[j];
}

// ---------------------------------------------------------------------------
// single-block exclusive scan, 16 elems/thread per chunk
// ---------------------------------------------------------------------------
__global__ __launch_bounds__(1024) void scan_kernel(const int* __restrict__ cnt,
                                                    int* __restrict__ out, int nn) {
    __shared__ int wsum[16];
    __shared__ int s_carry, s_tot;
    const int t = threadIdx.x;
    const int lane = t & 63;
    const int wid = t >> 6;
    if (t == 0) s_carry = 0;
    __syncthreads();
    const int CH = 16384;
    for (int chunk = 0; chunk < nn; chunk += CH) {
        const int i0 = chunk + t * 16;
        int c[16];
        if (i0 + 16 <= nn) {
#pragma unroll
            for (int q = 0; q < 4; ++q) {
                int4 v = *reinterpret_cast<const int4*>(cnt + i0 + q * 4);
                c[q * 4 + 0] = v.x; c[q * 4 + 1] = v.y;
                c[q * 4 + 2] = v.z; c[q * 4 + 3] = v.w;
            }
        } else {
#pragma unroll
            for (int q = 0; q < 16; ++q) c[q] = (i0 + q < nn) ? cnt[i0 + q] : 0;
        }
        int v = 0;
#pragma unroll
        for (int q = 0; q < 16; ++q) v += c[q];
        int s = v;
#pragma unroll
        for (int off = 1; off < 64; off <<= 1) {
            int y = __shfl_up(s, off, 64);
            if (lane >= off) s += y;
        }
        if (lane == 63) wsum[wid] = s;
        __syncthreads();
        if (t < 16) {
            int w = wsum[t];
            int ss = w;
#pragma unroll
            for (int off = 1; off < 16; off <<= 1) {
                int y = __shfl_up(ss, off, 16);
                if (t >= off) ss += y;
            }
            wsum[t] = ss - w;
            if (t == 15) s_tot = ss;
        }
        __syncthreads();
        int run = s_carry + wsum[wid] + (s - v);
        int o[16];
#pragma unroll
        for (int q = 0; q < 16; ++q) { o[q] = run; run += c[q]; }
        if (i0 + 16 <= nn) {
#pragma unroll
            for (int q = 0; q < 4; ++q)
                *reinterpret_cast<int4*>(out + i0 + q * 4) =
                    make_int4(o[q * 4], o[q * 4 + 1], o[q * 4 + 2], o[q * 4 + 3]);
        } else {
#pragma unroll
            for (int q = 0; q < 16; ++q) if (i0 + q < nn) out[i0 + q] = o[q];
        }
        __syncthreads();
        if (t == 0) s_carry += s_tot;
        __syncthreads();
    }
    if (t == 0) out[nn] = s_carry;
}

// ---------------------------------------------------------------------------
// placeB: append edges into private (partition, block) regions via LDS
// cursors. Write fronts are sequential 8B streams -> ~1x write amplification.
// ---------------------------------------------------------------------------
__global__ __launch_bounds__(256) void placeB_kernel(const int* __restrict__ src,
                                                     const int* __restrict__ dst,
                                                     const float* __restrict__ val,
                                                     const int* __restrict__ offs,
                                                     int2* __restrict__ tmp) {
    __shared__ int cur[NP];
    const int t = threadIdx.x, b = blockIdx.x;
    for (int p = t; p < NP; p += 256) cur[p] = offs[p * NBLKB + b];
    __syncthreads();
    const int e0 = b * EPB, e1 = e0 + EPB;
    for (int i = e0 + t; i < e1; i += 256) {
        int d = dst[i];
        int p = d >> 8;
        int pos = atomicAdd(&cur[p], 1);             // LDS atomic
        tmp[pos] = make_int2(src[i] | ((d & (PSZ - 1)) << 18), __float_as_int(val[i]));
    }
}

// ---------------------------------------------------------------------------
// phaseC: one block per partition. Pass 1: LDS node hist + LDS scan ->
// row_start. Pass 2: exact placement into an ~87KB L2-resident CSR window.
// ---------------------------------------------------------------------------
__global__ __launch_bounds__(256) void phaseC_kernel(const int2* __restrict__ tmp,
                                                     const int* __restrict__ offs,
                                                     int* __restrict__ row_start,
                                                     int2* __restrict__ csr) {
    __shared__ int hist[PSZ];
    __shared__ int cur[PSZ];
    __shared__ int wsum[4];
    const int p = blockIdx.x;
    const int t = threadIdx.x;
    const int lane = t & 63, wid = t >> 6;
    const int node0 = p * PSZ;
    const int nloc = min(PSZ, NN - node0);
    const int rb = offs[p * NBLKB];
    const int re = (p == NP - 1) ? NE : offs[(p + 1) * NBLKB];
    hist[t] = 0;
    __syncthreads();
    for (int i = rb + t; i < re; i += 256)
        atomicAdd(&hist[tmp[i].x >> 18], 1);         // LDS atomic
    __syncthreads();
    // exclusive scan of hist[0..256)
    int v = hist[t];
    int s = v;
#pragma unroll
    for (int off = 1; off < 64; off <<= 1) {
        int y = __shfl_up(s, off, 64);
        if (lane >= off) s += y;
    }
    if (lane == 63) wsum[wid] = s;
    __syncthreads();
    if (t == 0) {
        int a = wsum[0], b2 = wsum[1], c = wsum[2];
        wsum[1] = a; wsum[2] = a + b2; wsum[3] = a + b2 + c; wsum[0] = 0;
    }
    __syncthreads();
    int base = rb + wsum[wid] + (s - v);
    cur[t] = base;
    if (t < nloc) row_start[node0 + t] = base;
    if (p == 0 && t == 0) row_start[NN] = NE;
    __syncthreads();
    for (int i = rb + t; i < re; i += 256) {
        int2 e = tmp[i];
        int dl = e.x >> 18;
        int pos = atomicAdd(&cur[dl], 1);            // LDS atomic
        csr[pos] = make_int2(e.x & 0x3FFFF, e.y);
    }
}

// ---------------------------------------------------------------------------
// SpMM: one wave per dst row, lane = dim. M=0: first layer (reads emb tables,
// initializes acc). M=1: middle. M=2: last (no xout write).
// ---------------------------------------------------------------------------
template <int M>
__global__ __launch_bounds__(256) void spmm_kernel(const float* __restrict__ ue,
                                                   const float* __restrict__ ie,
                                                   const float* __restrict__ x,
                                                   float* __restrict__ xout,
                                                   float* __restrict__ acc,
                                                   const int* __restrict__ row_start,
                                                   const int2* __restrict__ csr) {
    int wave = (blockIdx.x << 2) | (threadIdx.x >> 6);
    int row = __builtin_amdgcn_readfirstlane(wave);
    if (row >= NN) return;
    const int lane = threadIdx.x & 63;
    int b = __builtin_amdgcn_readfirstlane(row_start[row]);
    int e = __builtin_amdgcn_readfirstlane(row_start[row + 1]);
    float a = 0.f;
    int i = b;
#define SRCROW(s) (M == 0 ? ((s) < NUSERS ? ue + (size_t)(s) * D : ie + (size_t)((s) - NUSERS) * D) \
                          : x + (size_t)(s) * D)
    for (; i + 4 <= e; i += 4) {
        int2 e0 = csr[i], e1 = csr[i + 1], e2 = csr[i + 2], e3 = csr[i + 3];
        a = fmaf(__int_as_float(e0.y), SRCROW(e0.x)[lane], a);
        a = fmaf(__int_as_float(e1.y), SRCROW(e1.x)[lane], a);
        a = fmaf(__int_as_float(e2.y), SRCROW(e2.x)[lane], a);
        a = fmaf(__int_as_float(e3.y), SRCROW(e3.x)[lane], a);
    }
    for (; i < e; ++i) {
        int2 e0 = csr[i];
        a = fmaf(__int_as_float(e0.y), SRCROW(e0.x)[lane], a);
    }
#undef SRCROW
    size_t o = (size_t)row * D + lane;
    if (M == 0) {
        float v = (row < NUSERS) ? ue[(size_t)row * D + lane]
                                 : ie[(size_t)(row - NUSERS) * D + lane];
        acc[o] = v + a;
        xout[o] = a;
    } else if (M == 1) {
        acc[o] += a;
        xout[o] = a;
    } else {
        acc[o] += a;
    }
}

__global__ void copy_items_kernel(const float4* __restrict__ acc4, float4* __restrict__ items4) {
    const int TOT4 = NITEMS * (D / 4);
    const int BASE4 = NUSERS * (D / 4);
    for (int i = blockIdx.x * blockDim.x + threadIdx.x; i < TOT4;
         i += gridDim.x * blockDim.x)
        items4[i] = acc4[BASE4 + i];
}

__global__ void ug_kernel(const float4* __restrict__ acc4, const int* __restrict__ users,
                          float4* __restrict__ ug4) {
    int i = blockIdx.x * blockDim.x + threadIdx.x;   // [0, QB*16)
    if (i >= QB * (D / 4)) return;
    int b = i >> 4;
    int k = i & 15;
    float4 v = acc4[(size_t)users[b] * (D / 4) + k];
    const float sc = 1.0f / 16.0f;                    // two folded /4 means
    ug4[i] = make_float4(v.x * sc, v.y * sc, v.z * sc, v.w * sc);
}

__global__ __launch_bounds__(256) void rating_kernel(const float* __restrict__ items_s,
                                                     const float* __restrict__ ug,
                                                     float* __restrict__ out) {
    const int i = blockIdx.x * 256 + threadIdx.x;
    const bool valid = i < NITEMS;
    const int ic = valid ? i : 0;
    float4 ir[16];
    const float4* irow = reinterpret_cast<const float4*>(items_s) + (size_t)ic * (D / 4);
#pragma unroll
    for (int k = 0; k < 16; ++k) ir[k] = irow[k];
    const float4* ug4 = reinterpret_cast<const float4*>(ug);
    const int u0 = blockIdx.y * 128;
    for (int g = 0; g < 16; ++g) {
        const int ub = u0 + g * 8;
        float s[8];
#pragma unroll
        for (int j = 0; j < 8; ++j) s[j] = 0.f;
#pragma unroll
        for (int k = 0; k < 16; ++k) {
            const float4 iv = ir[k];
#pragma unroll
            for (int j = 0; j < 8; ++j) {
                const float4 uv = ug4[(ub + j) * (D / 4) + k];
                s[j] = fmaf(iv.x, uv.x, s[j]);
                s[j] = fmaf(iv.y, uv.y, s[j]);
                s[j] = fmaf(iv.z, uv.z, s[j]);
                s[j] = fmaf(iv.w, uv.w, s[j]);
            }
        }
        if (valid) {
#pragma unroll
            for (int j = 0; j < 8; ++j) {
                float r = 1.0f / (1.0f + __expf(-s[j]));
                out[(size_t)(ub + j) * NITEMS + i] = r;
            }
        }
    }
}

extern "C" void kernel_launch(void* const* d_in, const int* in_sizes, int n_in,
                              void* d_out, int out_size, void* d_ws, size_t ws_size,
                              hipStream_t stream) {
    const float* user_emb = (const float*)d_in[0];
    const float* item_emb = (const float*)d_in[1];
    const float* edge_val = (const float*)d_in[2];
    const int*   edge_src = (const int*)d_in[3];
    const int*   edge_dst = (const int*)d_in[4];
    const int*   users    = (const int*)d_in[5];

    // d_out (51.2M floats) doubles as scratch; rating_kernel rewrites all of it
    // and reads only from d_ws.
    float* ob  = (float*)d_out;
    float* x0  = ob;                                   //  9.6M f (tmp lives here pre-spmm)
    float* x1  = x0 + (size_t)NN * D;                  //  9.6M f
    float* acc = x1 + (size_t)NN * D;                  //  9.6M f
    int2*  csr = (int2*)(acc + (size_t)NN * D);        //  6.4M int2 (51.2 MB)
    int*   row_start = (int*)(csr + NE);               //  150080 ints
    int*   counts    = row_start + 150080;             //  150016 ints
    int*   offs      = counts + 150016;                //  150080 ints
    int2*  tmp       = (int2*)x0;                      //  6.4M int2 over x0+x1 region

    // d_ws: only what rating_kernel reads (~13.1 MB)
    float* items_s = (float*)d_ws;                     // NITEMS*D
    float* ug      = items_s + (size_t)NITEMS * D;     // QB*D

    // CSR build — zero global atomics
    countB_kernel<<<NBLKB, 256, 0, stream>>>(edge_dst, counts);
    scan_kernel<<<1, 1024, 0, stream>>>(counts, offs, CNTN);
    placeB_kernel<<<NBLKB, 256, 0, stream>>>(edge_src, edge_dst, edge_val, offs, tmp);
    phaseC_kernel<<<NP, 256, 0, stream>>>(tmp, offs, row_start, csr);

    // 3 propagation layers (wave per row); layer 1 reads emb tables directly
    spmm_kernel<0><<<37500, 256, 0, stream>>>(user_emb, item_emb, nullptr, x1, acc,
                                              row_start, csr);
    spmm_kernel<1><<<37500, 256, 0, stream>>>(nullptr, nullptr, x1, x0, acc,
                                              row_start, csr);
    spmm_kernel<2><<<37500, 256, 0, stream>>>(nullptr, nullptr, x0, nullptr, acc,
                                              row_start, csr);

    copy_items_kernel<<<1024, 256, 0, stream>>>((const float4*)acc, (float4*)items_s);
    ug_kernel<<<64, 256, 0, stream>>>((const float4*)acc, users, (float4*)ug);

    rating_kernel<<<dim3((NITEMS + 255) / 256, QB / 128), 256, 0, stream>>>(items_s, ug, (float*)d_out);
}

// Round 4
// 938.084 us; speedup vs baseline: 2.4394x; 1.1590x over previous
//
#include <hip/hip_runtime.h>

#define NUSERS 100000
#define NITEMS 50000
#define NN (NUSERS + NITEMS)          // 150000 nodes
#define D 64
#define NE 6400000
#define QB 1024
#define PSZ 256                        // nodes per partition
#define NP ((NN + PSZ - 1) / PSZ)      // 586 partitions
#define NBLKB 256                      // countB/placeB blocks
#define EPB (NE / NBLKB)               // 25000 edges per block (exact)
#define CNTN (NP * NBLKB)              // 150016 counts

// ---------------------------------------------------------------------------
// countB: per-block LDS histogram over partitions -> counts[p][b]. No global
// atomics anywhere in the CSR build.
// ---------------------------------------------------------------------------
__global__ __launch_bounds__(256) void countB_kernel(const int* __restrict__ dst,
                                                     int* __restrict__ counts) {
    __shared__ int hist[NP];
    const int t = threadIdx.x, b = blockIdx.x;
    for (int j = t; j < NP; j += 256) hist[j] = 0;
    __syncthreads();
    const int e0 = b * EPB, e1 = e0 + EPB;
    for (int i = e0 + t; i < e1; i += 256)
        atomicAdd(&hist[dst[i] >> 8], 1);            // LDS atomic
    __syncthreads();
    for (int j = t; j < NP; j += 256)
        counts[j * NBLKB + b] = hist[j];
}

// ---------------------------------------------------------------------------
// single-block exclusive scan, 16 elems/thread per chunk
// ---------------------------------------------------------------------------
__global__ __launch_bounds__(1024) void scan_kernel(const int* __restrict__ cnt,
                                                    int* __restrict__ out, int nn) {
    __shared__ int wsum[16];
    __shared__ int s_carry, s_tot;
    const int t = threadIdx.x;
    const int lane = t & 63;
    const int wid = t >> 6;
    if (t == 0) s_carry = 0;
    __syncthreads();
    const int CH = 16384;
    for (int chunk = 0; chunk < nn; chunk += CH) {
        const int i0 = chunk + t * 16;
        int c[16];
        if (i0 + 16 <= nn) {
#pragma unroll
            for (int q = 0; q < 4; ++q) {
                int4 v = *reinterpret_cast<const int4*>(cnt + i0 + q * 4);
                c[q * 4 + 0] = v.x; c[q * 4 + 1] = v.y;
                c[q * 4 + 2] = v.z; c[q * 4 + 3] = v.w;
            }
        } else {
#pragma unroll
            for (int q = 0; q < 16; ++q) c[q] = (i0 + q < nn) ? cnt[i0 + q] : 0;
        }
        int v = 0;
#pragma unroll
        for (int q = 0; q < 16; ++q) v += c[q];
        int s = v;
#pragma unroll
        for (int off = 1; off < 64; off <<= 1) {
            int y = __shfl_up(s, off, 64);
            if (lane >= off) s += y;
        }
        if (lane == 63) wsum[wid] = s;
        __syncthreads();
        if (t < 16) {
            int w = wsum[t];
            int ss = w;
#pragma unroll
            for (int off = 1; off < 16; off <<= 1) {
                int y = __shfl_up(ss, off, 16);
                if (t >= off) ss += y;
            }
            wsum[t] = ss - w;
            if (t == 15) s_tot = ss;
        }
        __syncthreads();
        int run = s_carry + wsum[wid] + (s - v);
        int o[16];
#pragma unroll
        for (int q = 0; q < 16; ++q) { o[q] = run; run += c[q]; }
        if (i0 + 16 <= nn) {
#pragma unroll
            for (int q = 0; q < 4; ++q)
                *reinterpret_cast<int4*>(out + i0 + q * 4) =
                    make_int4(o[q * 4], o[q * 4 + 1], o[q * 4 + 2], o[q * 4 + 3]);
        } else {
#pragma unroll
            for (int q = 0; q < 16; ++q) if (i0 + q < nn) out[i0 + q] = o[q];
        }
        __syncthreads();
        if (t == 0) s_carry += s_tot;
        __syncthreads();
    }
    if (t == 0) out[nn] = s_carry;
}

// ---------------------------------------------------------------------------
// placeB: append edges into private (partition, block) regions via LDS
// cursors. Write fronts are sequential 8B streams -> ~1x write amplification.
// ---------------------------------------------------------------------------
__global__ __launch_bounds__(256) void placeB_kernel(const int* __restrict__ src,
                                                     const int* __restrict__ dst,
                                                     const float* __restrict__ val,
                                                     const int* __restrict__ offs,
                                                     int2* __restrict__ tmp) {
    __shared__ int cur[NP];
    const int t = threadIdx.x, b = blockIdx.x;
    for (int p = t; p < NP; p += 256) cur[p] = offs[p * NBLKB + b];
    __syncthreads();
    const int e0 = b * EPB, e1 = e0 + EPB;
    for (int i = e0 + t; i < e1; i += 256) {
        int d = dst[i];
        int p = d >> 8;
        int pos = atomicAdd(&cur[p], 1);             // LDS atomic
        tmp[pos] = make_int2(src[i] | ((d & (PSZ - 1)) << 18), __float_as_int(val[i]));
    }
}

// ---------------------------------------------------------------------------
// phaseC: one block per partition. Pass 1: LDS node hist + LDS scan ->
// row_start. Pass 2: exact placement into an ~87KB L2-resident CSR window.
// ---------------------------------------------------------------------------
__global__ __launch_bounds__(256) void phaseC_kernel(const int2* __restrict__ tmp,
                                                     const int* __restrict__ offs,
                                                     int* __restrict__ row_start,
                                                     int2* __restrict__ csr) {
    __shared__ int hist[PSZ];
    __shared__ int cur[PSZ];
    __shared__ int wsum[4];
    const int p = blockIdx.x;
    const int t = threadIdx.x;
    const int lane = t & 63, wid = t >> 6;
    const int node0 = p * PSZ;
    const int nloc = min(PSZ, NN - node0);
    const int rb = offs[p * NBLKB];
    const int re = (p == NP - 1) ? NE : offs[(p + 1) * NBLKB];
    hist[t] = 0;
    __syncthreads();
    for (int i = rb + t; i < re; i += 256)
        atomicAdd(&hist[tmp[i].x >> 18], 1);         // LDS atomic
    __syncthreads();
    // exclusive scan of hist[0..256)
    int v = hist[t];
    int s = v;
#pragma unroll
    for (int off = 1; off < 64; off <<= 1) {
        int y = __shfl_up(s, off, 64);
        if (lane >= off) s += y;
    }
    if (lane == 63) wsum[wid] = s;
    __syncthreads();
    if (t == 0) {
        int a = wsum[0], b2 = wsum[1], c = wsum[2];
        wsum[1] = a; wsum[2] = a + b2; wsum[3] = a + b2 + c; wsum[0] = 0;
    }
    __syncthreads();
    int base = rb + wsum[wid] + (s - v);
    cur[t] = base;
    if (t < nloc) row_start[node0 + t] = base;
    if (p == 0 && t == 0) row_start[NN] = NE;
    __syncthreads();
    for (int i = rb + t; i < re; i += 256) {
        int2 e = tmp[i];
        int dl = e.x >> 18;
        int pos = atomicAdd(&cur[dl], 1);            // LDS atomic
        csr[pos] = make_int2(e.x & 0x3FFFF, e.y);
    }
}

// ---------------------------------------------------------------------------
// gather helper: sum over a row's edges with 8-deep MLP
// ---------------------------------------------------------------------------
#define GATHER_LOOP(SRCROW)                                                    \
    {                                                                          \
        int i = b;                                                             \
        for (; i + 8 <= e; i += 8) {                                           \
            int2 E[8];                                                         \
            _Pragma("unroll")                                                  \
            for (int q = 0; q < 8; ++q) E[q] = csr[i + q];                     \
            float r[8];                                                        \
            _Pragma("unroll")                                                  \
            for (int q = 0; q < 8; ++q) r[q] = SRCROW(E[q].x)[lane];           \
            _Pragma("unroll")                                                  \
            for (int q = 0; q < 8; ++q)                                        \
                a = fmaf(__int_as_float(E[q].y), r[q], a);                     \
        }                                                                      \
        for (; i + 2 <= e; i += 2) {                                           \
            int2 e0 = csr[i], e1 = csr[i + 1];                                 \
            float r0 = SRCROW(e0.x)[lane];                                     \
            float r1 = SRCROW(e1.x)[lane];                                     \
            a = fmaf(__int_as_float(e0.y), r0, a);                             \
            a = fmaf(__int_as_float(e1.y), r1, a);                             \
        }                                                                      \
        if (i < e) {                                                           \
            int2 e0 = csr[i];                                                  \
            a = fmaf(__int_as_float(e0.y), SRCROW(e0.x)[lane], a);             \
        }                                                                      \
    }

// ---------------------------------------------------------------------------
// SpMM full layers. M=0: sources are emb tables, acc_items = ie + a (items).
// M=1: sources x, acc_items += a (items). Both write xout for ALL rows.
// acc is maintained for ITEM rows only (nothing reads user acc rows).
// ---------------------------------------------------------------------------
template <int M>
__global__ __launch_bounds__(256) void spmm_kernel(const float* __restrict__ ue,
                                                   const float* __restrict__ ie,
                                                   const float* __restrict__ x,
                                                   float* __restrict__ xout,
                                                   float* __restrict__ acc_items,
                                                   const int* __restrict__ row_start,
                                                   const int2* __restrict__ csr) {
    int wave = (blockIdx.x << 2) | (threadIdx.x >> 6);
    int row = __builtin_amdgcn_readfirstlane(wave);
    if (row >= NN) return;
    const int lane = threadIdx.x & 63;
    int b = __builtin_amdgcn_readfirstlane(row_start[row]);
    int e = __builtin_amdgcn_readfirstlane(row_start[row + 1]);
    float a = 0.f;
#define SRCROW(s) (M == 0 ? ((s) < NUSERS ? ue + (size_t)(s) * D : ie + (size_t)((s) - NUSERS) * D) \
                          : x + (size_t)(s) * D)
    GATHER_LOOP(SRCROW)
#undef SRCROW
    xout[(size_t)row * D + lane] = a;
    if (row >= NUSERS) {
        size_t o = (size_t)(row - NUSERS) * D + lane;
        if (M == 0)
            acc_items[o] = ie[o] + a;
        else
            acc_items[o] += a;
    }
}

// ---------------------------------------------------------------------------
// layer-3 SpMM over ITEM rows only; fuses the items_s production:
// items_s = acc_items + a  (unscaled; the /16 lives on the user side)
// ---------------------------------------------------------------------------
__global__ __launch_bounds__(256) void spmm_items_kernel(const float* __restrict__ x,
                                                         const float* __restrict__ acc_items,
                                                         const int* __restrict__ row_start,
                                                         const int2* __restrict__ csr,
                                                         float* __restrict__ items_s) {
    int wave = (blockIdx.x << 2) | (threadIdx.x >> 6);
    int it = __builtin_amdgcn_readfirstlane(wave);
    if (it >= NITEMS) return;
    const int row = NUSERS + it;
    const int lane = threadIdx.x & 63;
    int b = __builtin_amdgcn_readfirstlane(row_start[row]);
    int e = __builtin_amdgcn_readfirstlane(row_start[row + 1]);
    float a = 0.f;
#define SRCROW(s) (x + (size_t)(s) * D)
    GATHER_LOOP(SRCROW)
#undef SRCROW
    size_t o = (size_t)it * D + lane;
    items_s[o] = acc_items[o] + a;
}

// ---------------------------------------------------------------------------
// layer-3 for the QB queried users only (one wave per query):
// ug = (e0 + x1 + x2 + gather(x2)) / 16
// ---------------------------------------------------------------------------
__global__ __launch_bounds__(256) void user_final_kernel(const float* __restrict__ ue,
                                                         const float* __restrict__ x1,
                                                         const float* __restrict__ x2,
                                                         const int* __restrict__ users,
                                                         const int* __restrict__ row_start,
                                                         const int2* __restrict__ csr,
                                                         float* __restrict__ ug) {
    int w = (blockIdx.x << 2) | (threadIdx.x >> 6);   // 0..QB-1
    if (w >= QB) return;
    const int lane = threadIdx.x & 63;
    int row = __builtin_amdgcn_readfirstlane(users[w]);
    int b = __builtin_amdgcn_readfirstlane(row_start[row]);
    int e = __builtin_amdgcn_readfirstlane(row_start[row + 1]);
    float a = 0.f;
#define SRCROW(s) (x2 + (size_t)(s) * D)
    GATHER_LOOP(SRCROW)
#undef SRCROW
    size_t o = (size_t)row * D + lane;
    const float sc = 1.0f / 16.0f;                    // two folded /4 means
    ug[(size_t)w * D + lane] = (ue[o] + x1[o] + x2[o] + a) * sc;
}

__global__ __launch_bounds__(256) void rating_kernel(const float* __restrict__ items_s,
                                                     const float* __restrict__ ug,
                                                     float* __restrict__ out) {
    const int i = blockIdx.x * 256 + threadIdx.x;
    const bool valid = i < NITEMS;
    const int ic = valid ? i : 0;
    float4 ir[16];
    const float4* irow = reinterpret_cast<const float4*>(items_s) + (size_t)ic * (D / 4);
#pragma unroll
    for (int k = 0; k < 16; ++k) ir[k] = irow[k];
    const float4* ug4 = reinterpret_cast<const float4*>(ug);
    const int u0 = blockIdx.y * 128;
    for (int g = 0; g < 16; ++g) {
        const int ub = u0 + g * 8;
        float s[8];
#pragma unroll
        for (int j = 0; j < 8; ++j) s[j] = 0.f;
#pragma unroll
        for (int k = 0; k < 16; ++k) {
            const float4 iv = ir[k];
#pragma unroll
            for (int j = 0; j < 8; ++j) {
                const float4 uv = ug4[(ub + j) * (D / 4) + k];
                s[j] = fmaf(iv.x, uv.x, s[j]);
                s[j] = fmaf(iv.y, uv.y, s[j]);
                s[j] = fmaf(iv.z, uv.z, s[j]);
                s[j] = fmaf(iv.w, uv.w, s[j]);
            }
        }
        if (valid) {
#pragma unroll
            for (int j = 0; j < 8; ++j) {
                float r = 1.0f / (1.0f + __expf(-s[j]));
                out[(size_t)(ub + j) * NITEMS + i] = r;
            }
        }
    }
}

extern "C" void kernel_launch(void* const* d_in, const int* in_sizes, int n_in,
                              void* d_out, int out_size, void* d_ws, size_t ws_size,
                              hipStream_t stream) {
    const float* user_emb = (const float*)d_in[0];
    const float* item_emb = (const float*)d_in[1];
    const float* edge_val = (const float*)d_in[2];
    const int*   edge_src = (const int*)d_in[3];
    const int*   edge_dst = (const int*)d_in[4];
    const int*   users    = (const int*)d_in[5];

    // d_out (51.2M floats) doubles as scratch; rating_kernel rewrites all of it
    // and reads only from d_ws.
    float* ob  = (float*)d_out;
    float* x2  = ob;                                   //  9.6M f (tmp head pre-spmm)
    float* x1  = x2 + (size_t)NN * D;                  //  9.6M f (tmp tail overlaps head)
    float* acc = x1 + (size_t)NN * D;                  //  3.2M f (items only)
    int2*  csr = (int2*)(acc + (size_t)NITEMS * D);    //  6.4M int2 (51.2 MB)
    int*   row_start = (int*)(csr + NE);               //  150080 ints
    int*   counts    = row_start + 150080;             //  150016 ints
    int*   offs      = counts + 150016;                //  150080 ints
    int2*  tmp       = (int2*)x2;                      //  6.4M int2 over x2+x1 region

    // d_ws: only what rating_kernel reads (~13.1 MB)
    float* items_s = (float*)d_ws;                     // NITEMS*D
    float* ug      = items_s + (size_t)NITEMS * D;     // QB*D

    // CSR build — zero global atomics
    countB_kernel<<<NBLKB, 256, 0, stream>>>(edge_dst, counts);
    scan_kernel<<<1, 1024, 0, stream>>>(counts, offs, CNTN);
    placeB_kernel<<<NBLKB, 256, 0, stream>>>(edge_src, edge_dst, edge_val, offs, tmp);
    phaseC_kernel<<<NP, 256, 0, stream>>>(tmp, offs, row_start, csr);

    // layer 1 (all rows, sources = emb tables), layer 2 (all rows)
    spmm_kernel<0><<<37500, 256, 0, stream>>>(user_emb, item_emb, nullptr, x1, acc,
                                              row_start, csr);
    spmm_kernel<1><<<37500, 256, 0, stream>>>(nullptr, nullptr, x1, x2, acc,
                                              row_start, csr);
    // layer 3: item rows only (nothing reads user rows of acc) + queried users
    spmm_items_kernel<<<12500, 256, 0, stream>>>(x2, acc, row_start, csr, items_s);
    user_final_kernel<<<QB / 4, 256, 0, stream>>>(user_emb, x1, x2, users,
                                                  row_start, csr, ug);

    rating_kernel<<<dim3((NITEMS + 255) / 256, QB / 128), 256, 0, stream>>>(items_s, ug, (float*)d_out);
}

// Round 5
// 740.672 us; speedup vs baseline: 3.0896x; 1.2665x over previous
//
#include <hip/hip_runtime.h>
#include <hip/hip_fp16.h>

#define NUSERS 100000
#define NITEMS 50000
#define NN (NUSERS + NITEMS)          // 150000 nodes
#define D 64
#define NE 6400000
#define QB 1024
#define PSZ 256                        // nodes per partition
#define NP ((NN + PSZ - 1) / PSZ)      // 586 partitions
#define NBLKB 256                      // countB/placeB blocks
#define EPB (NE / NBLKB)               // 25000 edges per block (exact)
#define CNTN (NP * NBLKB)              // 150016 counts

// ---------------------------------------------------------------------------
// countB: per-block LDS histogram over partitions -> counts[p][b]. No global
// atomics anywhere in the CSR build.
// ---------------------------------------------------------------------------
__global__ __launch_bounds__(256) void countB_kernel(const int* __restrict__ dst,
                                                     int* __restrict__ counts) {
    __shared__ int hist[NP];
    const int t = threadIdx.x, b = blockIdx.x;
    for (int j = t; j < NP; j += 256) hist[j] = 0;
    __syncthreads();
    const int e0 = b * EPB, e1 = e0 + EPB;
    for (int i = e0 + t; i < e1; i += 256)
        atomicAdd(&hist[dst[i] >> 8], 1);            // LDS atomic
    __syncthreads();
    for (int j = t; j < NP; j += 256)
        counts[j * NBLKB + b] = hist[j];
}

// ---------------------------------------------------------------------------
// single-block exclusive scan, 16 elems/thread per chunk
// ---------------------------------------------------------------------------
__global__ __launch_bounds__(1024) void scan_kernel(const int* __restrict__ cnt,
                                                    int* __restrict__ out, int nn) {
    __shared__ int wsum[16];
    __shared__ int s_carry, s_tot;
    const int t = threadIdx.x;
    const int lane = t & 63;
    const int wid = t >> 6;
    if (t == 0) s_carry = 0;
    __syncthreads();
    const int CH = 16384;
    for (int chunk = 0; chunk < nn; chunk += CH) {
        const int i0 = chunk + t * 16;
        int c[16];
        if (i0 + 16 <= nn) {
#pragma unroll
            for (int q = 0; q < 4; ++q) {
                int4 v = *reinterpret_cast<const int4*>(cnt + i0 + q * 4);
                c[q * 4 + 0] = v.x; c[q * 4 + 1] = v.y;
                c[q * 4 + 2] = v.z; c[q * 4 + 3] = v.w;
            }
        } else {
#pragma unroll
            for (int q = 0; q < 16; ++q) c[q] = (i0 + q < nn) ? cnt[i0 + q] : 0;
        }
        int v = 0;
#pragma unroll
        for (int q = 0; q < 16; ++q) v += c[q];
        int s = v;
#pragma unroll
        for (int off = 1; off < 64; off <<= 1) {
            int y = __shfl_up(s, off, 64);
            if (lane >= off) s += y;
        }
        if (lane == 63) wsum[wid] = s;
        __syncthreads();
        if (t < 16) {
            int w = wsum[t];
            int ss = w;
#pragma unroll
            for (int off = 1; off < 16; off <<= 1) {
                int y = __shfl_up(ss, off, 16);
                if (t >= off) ss += y;
            }
            wsum[t] = ss - w;
            if (t == 15) s_tot = ss;
        }
        __syncthreads();
        int run = s_carry + wsum[wid] + (s - v);
        int o[16];
#pragma unroll
        for (int q = 0; q < 16; ++q) { o[q] = run; run += c[q]; }
        if (i0 + 16 <= nn) {
#pragma unroll
            for (int q = 0; q < 4; ++q)
                *reinterpret_cast<int4*>(out + i0 + q * 4) =
                    make_int4(o[q * 4], o[q * 4 + 1], o[q * 4 + 2], o[q * 4 + 3]);
        } else {
#pragma unroll
            for (int q = 0; q < 16; ++q) if (i0 + q < nn) out[i0 + q] = o[q];
        }
        __syncthreads();
        if (t == 0) s_carry += s_tot;
        __syncthreads();
    }
    if (t == 0) out[nn] = s_carry;
}

// ---------------------------------------------------------------------------
// placeB: append edges into private (partition, block) regions via LDS
// cursors. Write fronts are sequential 8B streams -> ~1x write amplification.
// ---------------------------------------------------------------------------
__global__ __launch_bounds__(256) void placeB_kernel(const int* __restrict__ src,
                                                     const int* __restrict__ dst,
                                                     const float* __restrict__ val,
                                                     const int* __restrict__ offs,
                                                     int2* __restrict__ tmp) {
    __shared__ int cur[NP];
    const int t = threadIdx.x, b = blockIdx.x;
    for (int p = t; p < NP; p += 256) cur[p] = offs[p * NBLKB + b];
    __syncthreads();
    const int e0 = b * EPB, e1 = e0 + EPB;
    for (int i = e0 + t; i < e1; i += 256) {
        int d = dst[i];
        int p = d >> 8;
        int pos = atomicAdd(&cur[p], 1);             // LDS atomic
        tmp[pos] = make_int2(src[i] | ((d & (PSZ - 1)) << 18), __float_as_int(val[i]));
    }
}

// ---------------------------------------------------------------------------
// phaseC: one block per partition. Pass 1: LDS node hist + LDS scan ->
// row_start. Pass 2: exact placement into an ~87KB L2-resident CSR window.
// ---------------------------------------------------------------------------
__global__ __launch_bounds__(256) void phaseC_kernel(const int2* __restrict__ tmp,
                                                     const int* __restrict__ offs,
                                                     int* __restrict__ row_start,
                                                     int2* __restrict__ csr) {
    __shared__ int hist[PSZ];
    __shared__ int cur[PSZ];
    __shared__ int wsum[4];
    const int p = blockIdx.x;
    const int t = threadIdx.x;
    const int lane = t & 63, wid = t >> 6;
    const int node0 = p * PSZ;
    const int nloc = min(PSZ, NN - node0);
    const int rb = offs[p * NBLKB];
    const int re = (p == NP - 1) ? NE : offs[(p + 1) * NBLKB];
    hist[t] = 0;
    __syncthreads();
    for (int i = rb + t; i < re; i += 256)
        atomicAdd(&hist[tmp[i].x >> 18], 1);         // LDS atomic
    __syncthreads();
    // exclusive scan of hist[0..256)
    int v = hist[t];
    int s = v;
#pragma unroll
    for (int off = 1; off < 64; off <<= 1) {
        int y = __shfl_up(s, off, 64);
        if (lane >= off) s += y;
    }
    if (lane == 63) wsum[wid] = s;
    __syncthreads();
    if (t == 0) {
        int a = wsum[0], b2 = wsum[1], c = wsum[2];
        wsum[1] = a; wsum[2] = a + b2; wsum[3] = a + b2 + c; wsum[0] = 0;
    }
    __syncthreads();
    int base = rb + wsum[wid] + (s - v);
    cur[t] = base;
    if (t < nloc) row_start[node0 + t] = base;
    if (p == 0 && t == 0) row_start[NN] = NE;
    __syncthreads();
    for (int i = rb + t; i < re; i += 256) {
        int2 e = tmp[i];
        int dl = e.x >> 18;
        int pos = atomicAdd(&cur[dl], 1);            // LDS atomic
        csr[pos] = make_int2(e.x & 0x3FFFF, e.y);
    }
}

// ---------------------------------------------------------------------------
// conv0: x0h = fp16(concat(user_emb, item_emb))
// ---------------------------------------------------------------------------
__global__ __launch_bounds__(256) void conv0_kernel(const float4* __restrict__ ue4,
                                                    const float4* __restrict__ ie4,
                                                    ushort4* __restrict__ x0) {
    const int U4 = NUSERS * (D / 4);
    const int T4 = NN * (D / 4);
    int i = blockIdx.x * 256 + threadIdx.x;
    if (i >= T4) return;
    float4 v = (i < U4) ? ue4[i] : ie4[i - U4];
    x0[i] = make_ushort4(__half_as_ushort(__float2half_rn(v.x)),
                         __half_as_ushort(__float2half_rn(v.y)),
                         __half_as_ushort(__float2half_rn(v.z)),
                         __half_as_ushort(__float2half_rn(v.w)));
}

// ---------------------------------------------------------------------------
// gather helper over fp16 source rows, 8-deep MLP, f32 accumulate
// ---------------------------------------------------------------------------
#define GATHER_LOOP_H(XH)                                                      \
    {                                                                          \
        int i = b;                                                             \
        for (; i + 8 <= e; i += 8) {                                           \
            int2 E[8];                                                         \
            _Pragma("unroll")                                                  \
            for (int q = 0; q < 8; ++q) E[q] = csr[i + q];                     \
            float r[8];                                                        \
            _Pragma("unroll")                                                  \
            for (int q = 0; q < 8; ++q)                                        \
                r[q] = __half2float(XH[(size_t)E[q].x * D + lane]);            \
            _Pragma("unroll")                                                  \
            for (int q = 0; q < 8; ++q)                                        \
                a = fmaf(__int_as_float(E[q].y), r[q], a);                     \
        }                                                                      \
        for (; i < e; ++i) {                                                   \
            int2 e0 = csr[i];                                                  \
            a = fmaf(__int_as_float(e0.y),                                     \
                     __half2float(XH[(size_t)e0.x * D + lane]), a);            \
        }                                                                      \
    }

// ---------------------------------------------------------------------------
// SpMM layers 1-2 (all rows), fp16 in / fp16 out, f32 acc for item rows.
// M=0: src=x0h, acc_items = ie + a. M=1: src=x1h, acc_items += a.
// ---------------------------------------------------------------------------
template <int M>
__global__ __launch_bounds__(256) void spmm_kernel(const __half* __restrict__ xh,
                                                   const float* __restrict__ ie,
                                                   __half* __restrict__ xout,
                                                   float* __restrict__ acc_items,
                                                   const int* __restrict__ row_start,
                                                   const int2* __restrict__ csr) {
    int wave = (blockIdx.x << 2) | (threadIdx.x >> 6);
    int row = __builtin_amdgcn_readfirstlane(wave);
    if (row >= NN) return;
    const int lane = threadIdx.x & 63;
    int b = __builtin_amdgcn_readfirstlane(row_start[row]);
    int e = __builtin_amdgcn_readfirstlane(row_start[row + 1]);
    float a = 0.f;
    GATHER_LOOP_H(xh)
    xout[(size_t)row * D + lane] = __float2half_rn(a);
    if (row >= NUSERS) {
        size_t o = (size_t)(row - NUSERS) * D + lane;
        if (M == 0)
            acc_items[o] = ie[o] + a;
        else
            acc_items[o] += a;
    }
}

// ---------------------------------------------------------------------------
// layer-3 SpMM over ITEM rows only; items_s = acc_items + a (f32, unscaled)
// ---------------------------------------------------------------------------
__global__ __launch_bounds__(256) void spmm_items_kernel(const __half* __restrict__ x2h,
                                                         const float* __restrict__ acc_items,
                                                         const int* __restrict__ row_start,
                                                         const int2* __restrict__ csr,
                                                         float* __restrict__ items_s) {
    int wave = (blockIdx.x << 2) | (threadIdx.x >> 6);
    int it = __builtin_amdgcn_readfirstlane(wave);
    if (it >= NITEMS) return;
    const int row = NUSERS + it;
    const int lane = threadIdx.x & 63;
    int b = __builtin_amdgcn_readfirstlane(row_start[row]);
    int e = __builtin_amdgcn_readfirstlane(row_start[row + 1]);
    float a = 0.f;
    GATHER_LOOP_H(x2h)
    size_t o = (size_t)it * D + lane;
    items_s[o] = acc_items[o] + a;
}

// ---------------------------------------------------------------------------
// layer-3 for the QB queried users only (one wave per query):
// ug = (e0 + x1 + x2 + gather(x2)) / 16
// ---------------------------------------------------------------------------
__global__ __launch_bounds__(256) void user_final_kernel(const float* __restrict__ ue,
                                                         const __half* __restrict__ x1h,
                                                         const __half* __restrict__ x2h,
                                                         const int* __restrict__ users,
                                                         const int* __restrict__ row_start,
                                                         const int2* __restrict__ csr,
                                                         float* __restrict__ ug) {
    int w = (blockIdx.x << 2) | (threadIdx.x >> 6);   // 0..QB-1
    if (w >= QB) return;
    const int lane = threadIdx.x & 63;
    int row = __builtin_amdgcn_readfirstlane(users[w]);
    int b = __builtin_amdgcn_readfirstlane(row_start[row]);
    int e = __builtin_amdgcn_readfirstlane(row_start[row + 1]);
    float a = 0.f;
    GATHER_LOOP_H(x2h)
    size_t o = (size_t)row * D + lane;
    const float sc = 1.0f / 16.0f;                    // two folded /4 means
    ug[(size_t)w * D + lane] =
        (ue[o] + __half2float(x1h[o]) + __half2float(x2h[o]) + a) * sc;
}

__global__ __launch_bounds__(256) void rating_kernel(const float* __restrict__ items_s,
                                                     const float* __restrict__ ug,
                                                     float* __restrict__ out) {
    const int i = blockIdx.x * 256 + threadIdx.x;
    const bool valid = i < NITEMS;
    const int ic = valid ? i : 0;
    float4 ir[16];
    const float4* irow = reinterpret_cast<const float4*>(items_s) + (size_t)ic * (D / 4);
#pragma unroll
    for (int k = 0; k < 16; ++k) ir[k] = irow[k];
    const float4* ug4 = reinterpret_cast<const float4*>(ug);
    const int u0 = blockIdx.y * 128;
    for (int g = 0; g < 16; ++g) {
        const int ub = u0 + g * 8;
        float s[8];
#pragma unroll
        for (int j = 0; j < 8; ++j) s[j] = 0.f;
#pragma unroll
        for (int k = 0; k < 16; ++k) {
            const float4 iv = ir[k];
#pragma unroll
            for (int j = 0; j < 8; ++j) {
                const float4 uv = ug4[(ub + j) * (D / 4) + k];
                s[j] = fmaf(iv.x, uv.x, s[j]);
                s[j] = fmaf(iv.y, uv.y, s[j]);
                s[j] = fmaf(iv.z, uv.z, s[j]);
                s[j] = fmaf(iv.w, uv.w, s[j]);
            }
        }
        if (valid) {
#pragma unroll
            for (int j = 0; j < 8; ++j) {
                float r = 1.0f / (1.0f + __expf(-s[j]));
                out[(size_t)(ub + j) * NITEMS + i] = r;
            }
        }
    }
}

extern "C" void kernel_launch(void* const* d_in, const int* in_sizes, int n_in,
                              void* d_out, int out_size, void* d_ws, size_t ws_size,
                              hipStream_t stream) {
    const float* user_emb = (const float*)d_in[0];
    const float* item_emb = (const float*)d_in[1];
    const float* edge_val = (const float*)d_in[2];
    const int*   edge_src = (const int*)d_in[3];
    const int*   edge_dst = (const int*)d_in[4];
    const int*   users    = (const int*)d_in[5];

    // d_out (204.8 MB) doubles as scratch; rating_kernel rewrites all of it
    // and reads only from d_ws. Total scratch use: ~174.6 MB.
    float*  ob  = (float*)d_out;
    int2*   csr = (int2*)ob;                           // 51.2 MB
    int2*   tmp = csr + NE;                            // 51.2 MB
    __half* x0h = (__half*)(tmp + NE);                 // 19.2 MB
    __half* x1h = x0h + (size_t)NN * D;                // 19.2 MB
    __half* x2h = x1h + (size_t)NN * D;                // 19.2 MB
    float*  acc = (float*)(x2h + (size_t)NN * D);      // 12.8 MB (items only)
    int*    row_start = (int*)(acc + (size_t)NITEMS * D); // 150080 ints
    int*    counts    = row_start + 150080;            // 150016 ints
    int*    offs      = counts + CNTN;                 // 150080 ints

    // d_ws: only what rating_kernel reads (~13.1 MB)
    float* items_s = (float*)d_ws;                     // NITEMS*D f32
    float* ug      = items_s + (size_t)NITEMS * D;     // QB*D f32

    // CSR build — zero global atomics
    countB_kernel<<<NBLKB, 256, 0, stream>>>(edge_dst, counts);
    scan_kernel<<<1, 1024, 0, stream>>>(counts, offs, CNTN);
    placeB_kernel<<<NBLKB, 256, 0, stream>>>(edge_src, edge_dst, edge_val, offs, tmp);
    phaseC_kernel<<<NP, 256, 0, stream>>>(tmp, offs, row_start, csr);

    // fp16 copy of the embedding tables (layer-1 gather source)
    conv0_kernel<<<(NN * (D / 4) + 255) / 256, 256, 0, stream>>>(
        (const float4*)user_emb, (const float4*)item_emb, (ushort4*)x0h);

    // layer 1 + layer 2 over all rows (fp16 gather, f32 accumulate)
    spmm_kernel<0><<<37500, 256, 0, stream>>>(x0h, item_emb, x1h, acc, row_start, csr);
    spmm_kernel<1><<<37500, 256, 0, stream>>>(x1h, nullptr, x2h, acc, row_start, csr);
    // layer 3: item rows only + queried users
    spmm_items_kernel<<<12500, 256, 0, stream>>>(x2h, acc, row_start, csr, items_s);
    user_final_kernel<<<QB / 4, 256, 0, stream>>>(user_emb, x1h, x2h, users,
                                                  row_start, csr, ug);

    rating_kernel<<<dim3((NITEMS + 255) / 256, QB / 128), 256, 0, stream>>>(items_s, ug, (float*)d_out);
}

// Round 6
// 627.814 us; speedup vs baseline: 3.6450x; 1.1798x over previous
//
#include <hip/hip_runtime.h>
#include <hip/hip_fp16.h>

#define NUSERS 100000
#define NITEMS 50000
#define NN (NUSERS + NITEMS)          // 150000 nodes
#define D 64
#define NE 6400000
#define QB 1024
#define PSZ 256                        // nodes per partition
#define NP ((NN + PSZ - 1) / PSZ)      // 586 partitions
#define NBLKB 256                      // countB/placeB blocks
#define EPB (NE / NBLKB)               // 25000 edges per block (exact)
#define CNTN (NP * NBLKB)              // 150016 counts
#define PB_CHUNK 4096                  // placeB LDS-staged chunk

// ---------------------------------------------------------------------------
// countB: per-block LDS histogram over partitions -> counts[p][b]. No global
// atomics anywhere in the CSR build.
// ---------------------------------------------------------------------------
__global__ __launch_bounds__(256) void countB_kernel(const int* __restrict__ dst,
                                                     int* __restrict__ counts) {
    __shared__ int hist[NP];
    const int t = threadIdx.x, b = blockIdx.x;
    for (int j = t; j < NP; j += 256) hist[j] = 0;
    __syncthreads();
    const int e0 = b * EPB, e1 = e0 + EPB;
    for (int i = e0 + t; i < e1; i += 256)
        atomicAdd(&hist[dst[i] >> 8], 1);            // LDS atomic
    __syncthreads();
    for (int j = t; j < NP; j += 256)
        counts[j * NBLKB + b] = hist[j];
}

// ---------------------------------------------------------------------------
// single-block exclusive scan, 16 elems/thread per chunk
// ---------------------------------------------------------------------------
__global__ __launch_bounds__(1024) void scan_kernel(const int* __restrict__ cnt,
                                                    int* __restrict__ out, int nn) {
    __shared__ int wsum[16];
    __shared__ int s_carry, s_tot;
    const int t = threadIdx.x;
    const int lane = t & 63;
    const int wid = t >> 6;
    if (t == 0) s_carry = 0;
    __syncthreads();
    const int CH = 16384;
    for (int chunk = 0; chunk < nn; chunk += CH) {
        const int i0 = chunk + t * 16;
        int c[16];
        if (i0 + 16 <= nn) {
#pragma unroll
            for (int q = 0; q < 4; ++q) {
                int4 v = *reinterpret_cast<const int4*>(cnt + i0 + q * 4);
                c[q * 4 + 0] = v.x; c[q * 4 + 1] = v.y;
                c[q * 4 + 2] = v.z; c[q * 4 + 3] = v.w;
            }
        } else {
#pragma unroll
            for (int q = 0; q < 16; ++q) c[q] = (i0 + q < nn) ? cnt[i0 + q] : 0;
        }
        int v = 0;
#pragma unroll
        for (int q = 0; q < 16; ++q) v += c[q];
        int s = v;
#pragma unroll
        for (int off = 1; off < 64; off <<= 1) {
            int y = __shfl_up(s, off, 64);
            if (lane >= off) s += y;
        }
        if (lane == 63) wsum[wid] = s;
        __syncthreads();
        if (t < 16) {
            int w = wsum[t];
            int ss = w;
#pragma unroll
            for (int off = 1; off < 16; off <<= 1) {
                int y = __shfl_up(ss, off, 16);
                if (t >= off) ss += y;
            }
            wsum[t] = ss - w;
            if (t == 15) s_tot = ss;
        }
        __syncthreads();
        int run = s_carry + wsum[wid] + (s - v);
        int o[16];
#pragma unroll
        for (int q = 0; q < 16; ++q) { o[q] = run; run += c[q]; }
        if (i0 + 16 <= nn) {
#pragma unroll
            for (int q = 0; q < 4; ++q)
                *reinterpret_cast<int4*>(out + i0 + q * 4) =
                    make_int4(o[q * 4], o[q * 4 + 1], o[q * 4 + 2], o[q * 4 + 3]);
        } else {
#pragma unroll
            for (int q = 0; q < 16; ++q) if (i0 + q < nn) out[i0 + q] = o[q];
        }
        __syncthreads();
        if (t == 0) s_carry += s_tot;
        __syncthreads();
    }
    if (t == 0) out[nn] = s_carry;
}

// ---------------------------------------------------------------------------
// placeB: per 4096-edge chunk, counting-sort by partition in LDS, then dump
// partition-ordered bursts into this block's (p,b) regions. Block-private
// LDS cursors; zero global atomics. 1024 threads -> 16 waves/CU.
// ---------------------------------------------------------------------------
__global__ __launch_bounds__(1024) void placeB_kernel(const int* __restrict__ src,
                                                      const int* __restrict__ dst,
                                                      const float* __restrict__ val,
                                                      const int* __restrict__ offs,
                                                      int2* __restrict__ tmp) {
    __shared__ int  cur[NP];               // running global cursor per partition
    __shared__ int  chist[NP];             // per-chunk counts
    __shared__ int  cbase[NP];             // per-chunk exclusive scan
    __shared__ int2 stage[PB_CHUNK];       // chunk edges sorted by partition
    __shared__ int  gpos[PB_CHUNK];        // global dest position per staged edge
    const int t = threadIdx.x, b = blockIdx.x;
    for (int p = t; p < NP; p += 1024) cur[p] = offs[p * NBLKB + b];
    const int e0 = b * EPB, e1 = e0 + EPB;
    for (int c0 = e0; c0 < e1; c0 += PB_CHUNK) {
        const int csize = min(PB_CHUNK, e1 - c0);
        for (int p = t; p < NP; p += 1024) chist[p] = 0;
        __syncthreads();
        // count + keep edges in registers
        int  ep[4], eslot[4];
        int2 epay[4];
#pragma unroll
        for (int q = 0; q < 4; ++q) {
            int i = c0 + t + q * 1024;
            ep[q] = -1;
            if (i < e1) {
                int d = dst[i];
                int p = d >> 8;
                ep[q] = p;
                epay[q] = make_int2(src[i] | ((d & (PSZ - 1)) << 18),
                                    __float_as_int(val[i]));
                eslot[q] = atomicAdd(&chist[p], 1);   // LDS atomic
            }
        }
        __syncthreads();
        // wave 0: exclusive scan of chist[0..NP) -> cbase
        if (t < 64) {
            const int per = (NP + 63) / 64;           // 10
            int base = t * per;
            int loc[(NP + 63) / 64];
            int run = 0;
#pragma unroll
            for (int q = 0; q < (NP + 63) / 64; ++q) {
                int idx = base + q;
                int c = (idx < NP) ? chist[idx] : 0;
                loc[q] = run; run += c;
            }
            int s = run;
#pragma unroll
            for (int off = 1; off < 64; off <<= 1) {
                int y = __shfl_up(s, off, 64);
                if (t >= off) s += y;
            }
            int excl = s - run;
#pragma unroll
            for (int q = 0; q < (NP + 63) / 64; ++q) {
                int idx = base + q;
                if (idx < NP) cbase[idx] = excl + loc[q];
            }
        }
        __syncthreads();
        // stage sorted by partition
#pragma unroll
        for (int q = 0; q < 4; ++q) {
            if (ep[q] >= 0) {
                int s = cbase[ep[q]] + eslot[q];
                stage[s] = epay[q];
                gpos[s]  = cur[ep[q]] + eslot[q];
            }
        }
        __syncthreads();
        // dump bursts + advance cursors
        for (int k = t; k < csize; k += 1024)
            tmp[gpos[k]] = stage[k];
        for (int p = t; p < NP; p += 1024) cur[p] += chist[p];
        __syncthreads();
    }
}

// ---------------------------------------------------------------------------
// phaseC: one block per partition, 1024 threads. Pass 1: LDS node hist + scan
// -> row_start. Pass 2: exact placement into an ~87KB L2-resident CSR window.
// ---------------------------------------------------------------------------
__global__ __launch_bounds__(1024) void phaseC_kernel(const int2* __restrict__ tmp,
                                                      const int* __restrict__ offs,
                                                      int* __restrict__ row_start,
                                                      int2* __restrict__ csr) {
    __shared__ int hist[PSZ];
    __shared__ int cur[PSZ];
    __shared__ int wsum[4];
    const int p = blockIdx.x;
    const int t = threadIdx.x;
    const int lane = t & 63, wid = t >> 6;
    const int node0 = p * PSZ;
    const int nloc = min(PSZ, NN - node0);
    const int rb = offs[p * NBLKB];
    const int re = (p == NP - 1) ? NE : offs[(p + 1) * NBLKB];
    if (t < PSZ) hist[t] = 0;
    __syncthreads();
    for (int i = rb + t; i < re; i += 1024)
        atomicAdd(&hist[tmp[i].x >> 18], 1);         // LDS atomic
    __syncthreads();
    int v = 0, s = 0;
    if (t < PSZ) {
        v = hist[t];
        s = v;
#pragma unroll
        for (int off = 1; off < 64; off <<= 1) {
            int y = __shfl_up(s, off, 64);
            if (lane >= off) s += y;
        }
        if (lane == 63) wsum[wid] = s;
    }
    __syncthreads();
    if (t == 0) {
        int a = wsum[0], b2 = wsum[1], c = wsum[2];
        wsum[1] = a; wsum[2] = a + b2; wsum[3] = a + b2 + c; wsum[0] = 0;
    }
    __syncthreads();
    if (t < PSZ) {
        int base = rb + wsum[wid] + (s - v);
        cur[t] = base;
        if (t < nloc) row_start[node0 + t] = base;
    }
    if (p == 0 && t == 0) row_start[NN] = NE;
    __syncthreads();
    for (int i = rb + t; i < re; i += 1024) {
        int2 e = tmp[i];
        int dl = e.x >> 18;
        int pos = atomicAdd(&cur[dl], 1);            // LDS atomic
        csr[pos] = make_int2(e.x & 0x3FFFF, e.y);
    }
}

// ---------------------------------------------------------------------------
// conv0: x0h = fp16(concat(user_emb, item_emb))
// ---------------------------------------------------------------------------
__global__ __launch_bounds__(256) void conv0_kernel(const float4* __restrict__ ue4,
                                                    const float4* __restrict__ ie4,
                                                    ushort4* __restrict__ x0) {
    const int U4 = NUSERS * (D / 4);
    const int T4 = NN * (D / 4);
    int i = blockIdx.x * 256 + threadIdx.x;
    if (i >= T4) return;
    float4 v = (i < U4) ? ue4[i] : ie4[i - U4];
    x0[i] = make_ushort4(__half_as_ushort(__float2half_rn(v.x)),
                         __half_as_ushort(__float2half_rn(v.y)),
                         __half_as_ushort(__float2half_rn(v.z)),
                         __half_as_ushort(__float2half_rn(v.w)));
}

// ---------------------------------------------------------------------------
// gather helper over fp16 source rows, 8-deep MLP, f32 accumulate
// ---------------------------------------------------------------------------
#define GATHER_LOOP_H(XH)                                                      \
    {                                                                          \
        int i = b;                                                             \
        for (; i + 8 <= e; i += 8) {                                           \
            int2 E[8];                                                         \
            _Pragma("unroll")                                                  \
            for (int q = 0; q < 8; ++q) E[q] = csr[i + q];                     \
            float r[8];                                                        \
            _Pragma("unroll")                                                  \
            for (int q = 0; q < 8; ++q)                                        \
                r[q] = __half2float(XH[(size_t)E[q].x * D + lane]);            \
            _Pragma("unroll")                                                  \
            for (int q = 0; q < 8; ++q)                                        \
                a = fmaf(__int_as_float(E[q].y), r[q], a);                     \
        }                                                                      \
        for (; i < e; ++i) {                                                   \
            int2 e0 = csr[i];                                                  \
            a = fmaf(__int_as_float(e0.y),                                     \
                     __half2float(XH[(size_t)e0.x * D + lane]), a);            \
        }                                                                      \
    }

// ---------------------------------------------------------------------------
// SpMM layers 1-2 (all rows), fp16 in / fp16 out, f32 acc for item rows.
// M=0: src=x0h, acc_items = ie + a. M=1: src=x1h, acc_items += a.
// ---------------------------------------------------------------------------
template <int M>
__global__ __launch_bounds__(256) void spmm_kernel(const __half* __restrict__ xh,
                                                   const float* __restrict__ ie,
                                                   __half* __restrict__ xout,
                                                   float* __restrict__ acc_items,
                                                   const int* __restrict__ row_start,
                                                   const int2* __restrict__ csr) {
    int wave = (blockIdx.x << 2) | (threadIdx.x >> 6);
    int row = __builtin_amdgcn_readfirstlane(wave);
    if (row >= NN) return;
    const int lane = threadIdx.x & 63;
    int b = __builtin_amdgcn_readfirstlane(row_start[row]);
    int e = __builtin_amdgcn_readfirstlane(row_start[row + 1]);
    float a = 0.f;
    GATHER_LOOP_H(xh)
    xout[(size_t)row * D + lane] = __float2half_rn(a);
    if (row >= NUSERS) {
        size_t o = (size_t)(row - NUSERS) * D + lane;
        if (M == 0)
            acc_items[o] = ie[o] + a;
        else
            acc_items[o] += a;
    }
}

// ---------------------------------------------------------------------------
// layer-3 SpMM over ITEM rows only; items_s = acc_items + a (f32, unscaled)
// ---------------------------------------------------------------------------
__global__ __launch_bounds__(256) void spmm_items_kernel(const __half* __restrict__ x2h,
                                                         const float* __restrict__ acc_items,
                                                         const int* __restrict__ row_start,
                                                         const int2* __restrict__ csr,
                                                         float* __restrict__ items_s) {
    int wave = (blockIdx.x << 2) | (threadIdx.x >> 6);
    int it = __builtin_amdgcn_readfirstlane(wave);
    if (it >= NITEMS) return;
    const int row = NUSERS + it;
    const int lane = threadIdx.x & 63;
    int b = __builtin_amdgcn_readfirstlane(row_start[row]);
    int e = __builtin_amdgcn_readfirstlane(row_start[row + 1]);
    float a = 0.f;
    GATHER_LOOP_H(x2h)
    size_t o = (size_t)it * D + lane;
    items_s[o] = acc_items[o] + a;
}

// ---------------------------------------------------------------------------
// layer-3 for the QB queried users only (one wave per query):
// ug = (e0 + x1 + x2 + gather(x2)) / 16
// ---------------------------------------------------------------------------
__global__ __launch_bounds__(256) void user_final_kernel(const float* __restrict__ ue,
                                                         const __half* __restrict__ x1h,
                                                         const __half* __restrict__ x2h,
                                                         const int* __restrict__ users,
                                                         const int* __restrict__ row_start,
                                                         const int2* __restrict__ csr,
                                                         float* __restrict__ ug) {
    int w = (blockIdx.x << 2) | (threadIdx.x >> 6);   // 0..QB-1
    if (w >= QB) return;
    const int lane = threadIdx.x & 63;
    int row = __builtin_amdgcn_readfirstlane(users[w]);
    int b = __builtin_amdgcn_readfirstlane(row_start[row]);
    int e = __builtin_amdgcn_readfirstlane(row_start[row + 1]);
    float a = 0.f;
    GATHER_LOOP_H(x2h)
    size_t o = (size_t)row * D + lane;
    const float sc = 1.0f / 16.0f;                    // two folded /4 means
    ug[(size_t)w * D + lane] =
        (ue[o] + __half2float(x1h[o]) + __half2float(x2h[o]) + a) * sc;
}

__global__ __launch_bounds__(256) void rating_kernel(const float* __restrict__ items_s,
                                                     const float* __restrict__ ug,
                                                     float* __restrict__ out) {
    const int i = blockIdx.x * 256 + threadIdx.x;
    const bool valid = i < NITEMS;
    const int ic = valid ? i : 0;
    float4 ir[16];
    const float4* irow = reinterpret_cast<const float4*>(items_s) + (size_t)ic * (D / 4);
#pragma unroll
    for (int k = 0; k < 16; ++k) ir[k] = irow[k];
    const float4* ug4 = reinterpret_cast<const float4*>(ug);
    const int u0 = blockIdx.y * 128;
    for (int g = 0; g < 16; ++g) {
        const int ub = u0 + g * 8;
        float s[8];
#pragma unroll
        for (int j = 0; j < 8; ++j) s[j] = 0.f;
#pragma unroll
        for (int k = 0; k < 16; ++k) {
            const float4 iv = ir[k];
#pragma unroll
            for (int j = 0; j < 8; ++j) {
                const float4 uv = ug4[(ub + j) * (D / 4) + k];
                s[j] = fmaf(iv.x, uv.x, s[j]);
                s[j] = fmaf(iv.y, uv.y, s[j]);
                s[j] = fmaf(iv.z, uv.z, s[j]);
                s[j] = fmaf(iv.w, uv.w, s[j]);
            }
        }
        if (valid) {
#pragma unroll
            for (int j = 0; j < 8; ++j) {
                float r = 1.0f / (1.0f + __expf(-s[j]));
                out[(size_t)(ub + j) * NITEMS + i] = r;
            }
        }
    }
}

extern "C" void kernel_launch(void* const* d_in, const int* in_sizes, int n_in,
                              void* d_out, int out_size, void* d_ws, size_t ws_size,
                              hipStream_t stream) {
    const float* user_emb = (const float*)d_in[0];
    const float* item_emb = (const float*)d_in[1];
    const float* edge_val = (const float*)d_in[2];
    const int*   edge_src = (const int*)d_in[3];
    const int*   edge_dst = (const int*)d_in[4];
    const int*   users    = (const int*)d_in[5];

    // d_out (204.8 MB) doubles as scratch; rating_kernel rewrites all of it
    // and reads only from d_ws. Total scratch use: ~174.6 MB.
    float*  ob  = (float*)d_out;
    int2*   csr = (int2*)ob;                           // 51.2 MB
    int2*   tmp = csr + NE;                            // 51.2 MB
    __half* x0h = (__half*)(tmp + NE);                 // 19.2 MB
    __half* x1h = x0h + (size_t)NN * D;                // 19.2 MB
    __half* x2h = x1h + (size_t)NN * D;                // 19.2 MB
    float*  acc = (float*)(x2h + (size_t)NN * D);      // 12.8 MB (items only)
    int*    row_start = (int*)(acc + (size_t)NITEMS * D); // 150080 ints
    int*    counts    = row_start + 150080;            // 150016 ints
    int*    offs      = counts + CNTN;                 // 150080 ints

    // d_ws: only what rating_kernel reads (~13.1 MB)
    float* items_s = (float*)d_ws;                     // NITEMS*D f32
    float* ug      = items_s + (size_t)NITEMS * D;     // QB*D f32

    // CSR build — zero global atomics
    countB_kernel<<<NBLKB, 256, 0, stream>>>(edge_dst, counts);
    scan_kernel<<<1, 1024, 0, stream>>>(counts, offs, CNTN);
    placeB_kernel<<<NBLKB, 1024, 0, stream>>>(edge_src, edge_dst, edge_val, offs, tmp);
    phaseC_kernel<<<NP, 1024, 0, stream>>>(tmp, offs, row_start, csr);

    // fp16 copy of the embedding tables (layer-1 gather source)
    conv0_kernel<<<(NN * (D / 4) + 255) / 256, 256, 0, stream>>>(
        (const float4*)user_emb, (const float4*)item_emb, (ushort4*)x0h);

    // layer 1 + layer 2 over all rows (fp16 gather, f32 accumulate)
    spmm_kernel<0><<<37500, 256, 0, stream>>>(x0h, item_emb, x1h, acc, row_start, csr);
    spmm_kernel<1><<<37500, 256, 0, stream>>>(x1h, nullptr, x2h, acc, row_start, csr);
    // layer 3: item rows only + queried users
    spmm_items_kernel<<<12500, 256, 0, stream>>>(x2h, acc, row_start, csr, items_s);
    user_final_kernel<<<QB / 4, 256, 0, stream>>>(user_emb, x1h, x2h, users,
                                                  row_start, csr, ug);

    rating_kernel<<<dim3((NITEMS + 255) / 256, QB / 128), 256, 0, stream>>>(items_s, ug, (float*)d_out);
}